// Round 10
// baseline (141.685 us; speedup 1.0000x reference)
//
#include <hip/hip_runtime.h>

// Smith-Waterman soft-DP, B=512, x: (512,151,151) f32, scalar output.
// One wave per TWO batches (grid 256): the two independent DP chains are
// interleaved in one wave to convert TLP (which is capped at 512 waves on
// 1024 SIMDs) into ILP. Linear-domain DP (H = exp(h) * 2^-E), x staged as
// exp-domain f16 in LDS (2 x 45.6 KB), 4-step static register FIFO, DPP
// neighbor exchange. Per-step scalar/address work shared across batches.

#define CGO 6.737946999085467e-03f   // e^-5
#define CGE 3.678794411714423e-01f   // e^-1
#define L2E 1.4426950408889634f
#define LN2 0.6931471805599453f
#define RTHR 0x1p60f
#define RSC  0x1p-64f

#if __has_builtin(__builtin_amdgcn_exp2f)
#define EXP2(x) __builtin_amdgcn_exp2f(x)
#else
static __device__ __forceinline__ float EXP2_(float x){float r;asm("v_exp_f32 %0, %1":"=v"(r):"v"(x));return r;}
#define EXP2(x) EXP2_(x)
#endif

#if __has_builtin(__builtin_amdgcn_logf)
#define LOG2(x) __builtin_amdgcn_logf(x)
#else
static __device__ __forceinline__ float LOG2_(float x){float r;asm("v_log_f32 %0, %1":"=v"(r):"v"(x));return r;}
#define LOG2(x) LOG2_(x)
#endif

static __device__ __forceinline__ float rl(float v, int l){
    return __int_as_float(__builtin_amdgcn_readlane(__float_as_int(v), l));
}

#define DPP_UP 0x138   // wave_shr:1  (lane i <- i-1)
#define DPP_DN 0x130   // wave_shl:1  (lane i <- i+1)

template<int CTRL>
static __device__ __forceinline__ float dppz(float v){   // invalid lanes -> 0
    return __int_as_float(__builtin_amdgcn_update_dpp(
        0, __float_as_int(v), CTRL, 0xF, 0xF, true));
}
template<int CTRL>
static __device__ __forceinline__ float dppc(float old, float v){ // invalid -> old
    return __int_as_float(__builtin_amdgcn_update_dpp(
        __float_as_int(old), __float_as_int(v), CTRL, 0xF, 0xF, false));
}

// row-major LDS word index of diag-t, slot-j cell (j given as 150*j + 9600*k)
static __device__ __forceinline__ int cellIdx(int t, int j150k){
    const int halfT = (149 + t) >> 1;
    int idx = 150 * halfT + t - j150k;
    idx = idx < 0 ? 0 : idx;
    idx = idx > 22800 ? 22800 : idx;
    return idx;
}

// ---- one anti-diagonal step for BOTH batches (SO = d&1; K2 = do k=2) ----
// Per batch q: Vs = exp(cell) diag d, Vx = diag d+2, Rc = raw f16 diag d+4.
// Issues LDS reads for diag d+8; commits Vs <- cvt(Rc), Rc <- new.
template<int SO, bool K2>
static __device__ __forceinline__
void stepF(const int d, const int lane, const int j150,
           const _Float16* __restrict__ ldsH,
           float (&H1)[2][3][3], float (&H2)[2][3][3],
           float (&Vs)[2][3], float (&Vx)[2][3], _Float16 (&Rc)[2][3],
           const float (&oneE)[2], float (&S)[2])
{
    const int half = (149 + d) >> 1;
    const int cvlo = half - (d < 149 ? d : 149);
    const int cvhi = half - (d > 149 ? d - 149 : 0);

    // shared addresses; two ds_read_u16 per address (batch offsets 0 / 45632)
    int ci[3];
    #pragma unroll
    for (int k = 0; k < 3; ++k) ci[k] = cellIdx(d + 8, j150 + 9600 * k);
    _Float16 l[2][3];
    #pragma unroll
    for (int q = 0; q < 2; ++q)
        #pragma unroll
        for (int k = 0; k < 3; ++k)
            l[q][k] = ldsH[q * 22816 + ci[k]];

    // neighbor gather from H1 via DPP, per batch
    float n0[2][3], n1[2][3], n2[2][3];
    #pragma unroll
    for (int q = 0; q < 2; ++q) {
        if (SO) {   // odd: "right" uses h1[j-1], comps 0,1
            n0[q][0] = dppz<DPP_UP>(H1[q][0][0]);
            n1[q][0] = dppz<DPP_UP>(H1[q][0][1]);
            n0[q][1] = dppc<DPP_UP>(rl(H1[q][0][0], 63), H1[q][1][0]);
            n1[q][1] = dppc<DPP_UP>(rl(H1[q][0][1], 63), H1[q][1][1]);
            n0[q][2] = dppc<DPP_UP>(rl(H1[q][1][0], 63), H1[q][2][0]);
            n1[q][2] = dppc<DPP_UP>(rl(H1[q][1][1], 63), H1[q][2][1]);
            n2[q][0] = n2[q][1] = n2[q][2] = 0.0f;
        } else {    // even: "down" uses h1[j+1], comps 0,1,2
            n0[q][2] = dppz<DPP_DN>(H1[q][2][0]);
            n1[q][2] = dppz<DPP_DN>(H1[q][2][1]);
            n2[q][2] = dppz<DPP_DN>(H1[q][2][2]);
            n0[q][1] = dppc<DPP_DN>(rl(H1[q][2][0], 0), H1[q][1][0]);
            n1[q][1] = dppc<DPP_DN>(rl(H1[q][2][1], 0), H1[q][1][1]);
            n2[q][1] = dppc<DPP_DN>(rl(H1[q][2][2], 0), H1[q][1][2]);
            n0[q][0] = dppc<DPP_DN>(rl(H1[q][1][0], 0), H1[q][0][0]);
            n1[q][0] = dppc<DPP_DN>(rl(H1[q][1][1], 0), H1[q][0][1]);
            n2[q][0] = dppc<DPP_DN>(rl(H1[q][1][2], 0), H1[q][0][2]);
        }
    }

    #pragma unroll
    for (int k = 0; k < 3; ++k) {
        if (k == 2 && !K2) continue;
        const int lo = cvlo - 64 * k, hi = cvhi - 64 * k;
        const bool cv = (lane >= lo) && (lane <= hi);
        #pragma unroll
        for (int q = 0; q < 2; ++q) {
            const float sxl = cv ? Vs[q][k] : 0.0f;
            const float x2l = cv ? Vx[q][k] : 0.0f;

            float h0 = sxl * (((H2[q][k][0] + H2[q][k][1]) + H2[q][k][2]) + oneE[q]);
            float h1, h2;
            if (SO) {
                h1 = fmaf(CGO, n0[q][k], CGE * n1[q][k]);
                h2 = fmaf(CGO, H1[q][k][0] + H1[q][k][1], CGE * H1[q][k][2]);
            } else {
                h1 = fmaf(CGO, H1[q][k][0], CGE * H1[q][k][1]);
                h2 = fmaf(CGO, n0[q][k] + n1[q][k], CGE * n2[q][k]);
            }
            if (k == 2) {   // slots >= 150 don't exist
                const bool pad = lane >= 22;
                h0 = pad ? 0.0f : h0;
                h1 = pad ? 0.0f : h1;
                h2 = pad ? 0.0f : h2;
            }
            S[q] = fmaf(x2l, (h0 + h1) + h2, S[q]);
            H2[q][k][0] = h0; H2[q][k][1] = h1; H2[q][k][2] = h2;
        }
    }

    // FIFO: commit (cvt) diag d+4, insert new raw diag d+8
    #pragma unroll
    for (int q = 0; q < 2; ++q)
        #pragma unroll
        for (int k = 0; k < 3; ++k) {
            Vs[q][k] = (float)Rc[q][k];
            Rc[q][k] = l[q][k];
        }
}

__global__ __launch_bounds__(64)
void sw_fused2(const float* __restrict__ x, float* __restrict__ part,
               float* __restrict__ out_atomic, int use_atomic) {
    const int b = blockIdx.x;          // handles batches 2b and 2b+1
    const int lane = threadIdx.x;
    const int j150 = 150 * lane;

    __shared__ _Float16 ldsH[2 * 22816];   // per-batch row-major exp2(x*log2e)

    // ---- phase A: coalesced load + exp into LDS (single wave, no barrier) ----
    #pragma unroll
    for (int q = 0; q < 2; ++q) {
        const float* xq = x + (size_t)(2 * b + q) * 22801;
        const int base = q * 22816;
        for (int ii = 0; ii < 356; ++ii) {
            const int idx = ii * 64 + lane;
            ldsH[base + idx] = (_Float16)EXP2(xq[idx] * L2E);
        }
        if (lane < 17) {
            const int idx = 22784 + lane;
            ldsH[base + idx] = (_Float16)EXP2(xq[idx] * L2E);
        }
    }

    // ---- phase B: two interleaved DPs ----
    float Ha[2][3][3], Hb[2][3][3];
    #pragma unroll
    for (int q = 0; q < 2; ++q)
        #pragma unroll
        for (int k = 0; k < 3; ++k)
            #pragma unroll
            for (int c = 0; c < 3; ++c) { Ha[q][k][c] = 0.0f; Hb[q][k][c] = 0.0f; }

    float V0[2][3], V1[2][3], V2[2][3], V3[2][3];
    _Float16 R0[2][3], R1[2][3], R2[2][3], R3[2][3];
    #pragma unroll
    for (int q = 0; q < 2; ++q) {
        const int base = q * 22816;
        #pragma unroll
        for (int k = 0; k < 3; ++k) {
            const int jk = j150 + 9600 * k;
            V0[q][k] = (float)ldsH[base + cellIdx(0, jk)];
            V1[q][k] = (float)ldsH[base + cellIdx(1, jk)];
            V2[q][k] = (float)ldsH[base + cellIdx(2, jk)];
            V3[q][k] = (float)ldsH[base + cellIdx(3, jk)];
            R0[q][k] = ldsH[base + cellIdx(4, jk)];
            R1[q][k] = ldsH[base + cellIdx(5, jk)];
            R2[q][k] = ldsH[base + cellIdx(6, jk)];
            R3[q][k] = ldsH[base + cellIdx(7, jk)];
        }
    }

    float oneE[2] = {1.0f, 1.0f};
    float E[2] = {0.0f, 0.0f};
    float S[2] = {0.0f, 0.0f};

    #define RENORM() do {                                                      \
        _Pragma("unroll")                                                      \
        for (int q_ = 0; q_ < 2; ++q_) {                                       \
            float m_ = Hb[q_][0][0];                                           \
            m_ = fmaxf(m_, Hb[q_][0][1]); m_ = fmaxf(m_, Hb[q_][0][2]);        \
            m_ = fmaxf(m_, Hb[q_][1][0]); m_ = fmaxf(m_, Hb[q_][1][1]);        \
            m_ = fmaxf(m_, Hb[q_][1][2]); m_ = fmaxf(m_, Hb[q_][2][0]);        \
            m_ = fmaxf(m_, Hb[q_][2][1]); m_ = fmaxf(m_, Hb[q_][2][2]);        \
            const bool rn_ = __any(m_ > RTHR);                                 \
            const float sc_ = rn_ ? RSC : 1.0f;                                \
            _Pragma("unroll")                                                  \
            for (int k_ = 0; k_ < 3; ++k_)                                     \
                _Pragma("unroll")                                              \
                for (int c_ = 0; c_ < 3; ++c_) {                               \
                    Ha[q_][k_][c_] *= sc_; Hb[q_][k_][c_] *= sc_;              \
                }                                                              \
            S[q_] *= sc_; oneE[q_] *= sc_; E[q_] += rn_ ? 64.0f : 0.0f;        \
        }                                                                      \
    } while (0)

    // region A: d in [0,92), k2 block compiled out (first active at d=95)
    for (int d = 0; d < 92; d += 4) {
        stepF<0,false>(d + 0, lane, j150, ldsH, Hb, Ha, V0, V2, R0, oneE, S);
        stepF<1,false>(d + 1, lane, j150, ldsH, Ha, Hb, V1, V3, R1, oneE, S);
        stepF<0,false>(d + 2, lane, j150, ldsH, Hb, Ha, V2, V0, R2, oneE, S);
        stepF<1,false>(d + 3, lane, j150, ldsH, Ha, Hb, V3, V1, R3, oneE, S);
        RENORM();
    }
    // region B: d in [92,296), all k
    for (int d = 92; d < 296; d += 4) {
        stepF<0,true>(d + 0, lane, j150, ldsH, Hb, Ha, V0, V2, R0, oneE, S);
        stepF<1,true>(d + 1, lane, j150, ldsH, Ha, Hb, V1, V3, R1, oneE, S);
        stepF<0,true>(d + 2, lane, j150, ldsH, Hb, Ha, V2, V0, R2, oneE, S);
        stepF<1,true>(d + 3, lane, j150, ldsH, Ha, Hb, V3, V1, R3, oneE, S);
        RENORM();
    }
    // tail: diags 296..298
    stepF<0,true>(296, lane, j150, ldsH, Hb, Ha, V0, V2, R0, oneE, S);
    stepF<1,true>(297, lane, j150, ldsH, Ha, Hb, V1, V3, R1, oneE, S);
    stepF<0,true>(298, lane, j150, ldsH, Hb, Ha, V2, V0, R2, oneE, S);

    // wave sum of S per batch (E uniform across lanes)
    #pragma unroll
    for (int q = 0; q < 2; ++q) {
        float Sq = S[q];
        #pragma unroll
        for (int off = 32; off; off >>= 1) Sq += __shfl_xor(Sq, off, 64);
        if (lane == 0) {
            const float val = LN2 * (E[q] + LOG2(Sq));
            if (use_atomic) atomicAdd(out_atomic, val);
            else            part[2 * b + q] = val;
        }
    }
}

__global__ __launch_bounds__(256)
void final_reduce(const float* __restrict__ part, float* __restrict__ out) {
    const int t = threadIdx.x;
    float v = part[t] + part[t + 256];
    #pragma unroll
    for (int off = 32; off; off >>= 1) v += __shfl_xor(v, off);
    __shared__ float ws[4];
    if ((t & 63) == 0) ws[t >> 6] = v;
    __syncthreads();
    if (t == 0) out[0] = ws[0] + ws[1] + ws[2] + ws[3];
}

extern "C" void kernel_launch(void* const* d_in, const int* in_sizes, int n_in,
                              void* d_out, int out_size, void* d_ws, size_t ws_size,
                              hipStream_t stream) {
    const float* x = (const float*)d_in[0];
    float* out = (float*)d_out;

    if (ws_size >= 512 * sizeof(float)) {
        float* part = (float*)d_ws;
        sw_fused2<<<256, 64, 0, stream>>>(x, part, nullptr, 0);
        final_reduce<<<1, 256, 0, stream>>>(part, out);
    } else {
        hipMemsetAsync(out, 0, sizeof(float), stream);
        sw_fused2<<<256, 64, 0, stream>>>(x, nullptr, out, 1);
    }
}

// Round 11
// 85.648 us; speedup vs baseline: 1.6543x; 1.6543x over previous
//
#include <hip/hip_runtime.h>

// Smith-Waterman soft-DP, B=512, x: (512,151,151) f32, scalar output.
// One wave per batch (512 blocks). Linear-domain DP (H = exp(h) * 2^-E).
// Phase A: coalesced read of x[b], exp2 -> f16 row-major LDS (45.6 KB).
// Phase B: slot packing j = 3*lane + k  ->  neighbor exchange is 2-3
// bound-ctrl DPPs per step (no readlane, no SGPR round-trips); 3
// ds_read_u16 per diagonal; 4-step static register FIFO; renorm every 4.

#define CGO 6.737946999085467e-03f   // e^-5
#define CGE 3.678794411714423e-01f   // e^-1
#define L2E 1.4426950408889634f
#define LN2 0.6931471805599453f
#define RTHR 0x1p60f
#define RSC  0x1p-64f

#if __has_builtin(__builtin_amdgcn_exp2f)
#define EXP2(x) __builtin_amdgcn_exp2f(x)
#else
static __device__ __forceinline__ float EXP2_(float x){float r;asm("v_exp_f32 %0, %1":"=v"(r):"v"(x));return r;}
#define EXP2(x) EXP2_(x)
#endif

#if __has_builtin(__builtin_amdgcn_logf)
#define LOG2(x) __builtin_amdgcn_logf(x)
#else
static __device__ __forceinline__ float LOG2_(float x){float r;asm("v_log_f32 %0, %1":"=v"(r):"v"(x));return r;}
#define LOG2(x) LOG2_(x)
#endif

#define DPP_UP 0x138   // wave_shr:1  (lane i <- i-1; lane 0 -> bound 0)
#define DPP_DN 0x130   // wave_shl:1  (lane i <- i+1; lane 63 -> bound 0)

template<int CTRL>
static __device__ __forceinline__ float dppz(float v){   // invalid lanes -> 0
    return __int_as_float(__builtin_amdgcn_update_dpp(
        0, __float_as_int(v), CTRL, 0xF, 0xF, true));
}

// ---- one anti-diagonal step (SO = d&1, compile-time) ----
// Slot j = 3*lane + k. Entry: Vs[k] = exp(cell) diag d, Vx[k] = diag d+2,
// Rc[k] = raw f16 diag d+4. Issues LDS reads for diag d+8; commits
// Vs <- cvt(Rc), Rc <- new. H1 = h(d-1), H2 = h(d-2) (overwritten with h(d)).
template<int SO>
static __device__ __forceinline__
void stepP(const int d, const int j3, const int jb0,
           const _Float16* __restrict__ ldsH,
           float (&H1)[3][3], float (&H2)[3][3],
           float (&Vs)[3], float (&Vx)[3], _Float16 (&Rc)[3],
           const float oneE, float& S, const bool isL50)
{
    const int half = (149 + d) >> 1;
    const int cvlo = half - (d < 149 ? d : 149);
    const int cvhi = half - (d > 149 ? d - 149 : 0);
    const int selS8 = 150 * half + d + 608;   // row-major addr base for diag d+8

    // LDS reads for diag d+8 (consumed 4 steps later)
    _Float16 l[3];
    #pragma unroll
    for (int k = 0; k < 3; ++k) {
        int idx = selS8 - jb0 - 150 * k;
        idx = idx < 0 ? 0 : idx;
        idx = idx > 22800 ? 22800 : idx;
        l[k] = ldsH[idx];
    }

    // neighbor components under packed mapping (h1 = H1)
    float R0[3], R1[3], D0[3], D1[3], D2[3];
    if (SO) {   // odd: right <- h1[j-1]; down <- own h1
        R0[0] = dppz<DPP_UP>(H1[2][0]);     // j-1 = 3(lane-1)+2
        R1[0] = dppz<DPP_UP>(H1[2][1]);
        R0[1] = H1[0][0]; R1[1] = H1[0][1]; // j-1 = own k=0
        R0[2] = H1[1][0]; R1[2] = H1[1][1]; // j-1 = own k=1
        #pragma unroll
        for (int k = 0; k < 3; ++k) { D0[k]=H1[k][0]; D1[k]=H1[k][1]; D2[k]=H1[k][2]; }
    } else {    // even: right <- own h1; down <- h1[j+1]
        #pragma unroll
        for (int k = 0; k < 3; ++k) { R0[k]=H1[k][0]; R1[k]=H1[k][1]; }
        D0[0] = H1[1][0]; D1[0] = H1[1][1]; D2[0] = H1[1][2];  // j+1 = own k=1
        D0[1] = H1[2][0]; D1[1] = H1[2][1]; D2[1] = H1[2][2];  // j+1 = own k=2
        D0[2] = dppz<DPP_DN>(H1[0][0]);     // j+1 = 3(lane+1)+0
        D1[2] = dppz<DPP_DN>(H1[0][1]);
        D2[2] = dppz<DPP_DN>(H1[0][2]);
    }

    #pragma unroll
    for (int k = 0; k < 3; ++k) {
        const int j = j3 + k;
        const bool cv = (j >= cvlo) && (j <= cvhi);
        const float sxl = cv ? Vs[k] : 0.0f;
        const float x2l = cv ? Vx[k] : 0.0f;

        float h0 = sxl * ((H2[k][0] + H2[k][1]) + (H2[k][2] + oneE));
        float h1 = fmaf(CGO, R0[k], CGE * R1[k]);
        float h2 = fmaf(CGO, D0[k] + D1[k], CGE * D2[k]);
        if (k == 0) {   // slot 150 (lane 50, k=0) is the only pad slot a real
            h1 = isL50 ? 0.0f : h1;   // cell ever reads; force exact sentinel.
            h2 = isL50 ? 0.0f : h2;   // (h0 already 0 via cv.) Slots 151+ stay 0.
        }
        S = fmaf(x2l, (h0 + h1) + h2, S);
        H2[k][0] = h0; H2[k][1] = h1; H2[k][2] = h2;
    }

    // FIFO: commit (cvt) diag d+4, insert new raw diag d+8
    Vs[0] = (float)Rc[0]; Vs[1] = (float)Rc[1]; Vs[2] = (float)Rc[2];
    Rc[0] = l[0]; Rc[1] = l[1]; Rc[2] = l[2];
}

__global__ __launch_bounds__(64)
void sw_pack(const float* __restrict__ x, float* __restrict__ part,
             float* __restrict__ out_atomic, int use_atomic) {
    const int b = blockIdx.x;
    const float* xb = x + (size_t)b * 22801;
    const int lane = threadIdx.x;
    const int j3  = 3 * lane;       // slot of k=0
    const int jb0 = 450 * lane;     // 150 * j3
    const bool isL50 = (lane == 50);

    __shared__ _Float16 ldsH[22816];   // row-major exp2(x*log2e), f16

    // ---- phase A: coalesced load + exp into LDS ----
    for (int ii = 0; ii < 356; ++ii) {
        const int idx = ii * 64 + lane;
        ldsH[idx] = (_Float16)EXP2(xb[idx] * L2E);
    }
    if (lane < 17) {
        const int idx = 22784 + lane;
        ldsH[idx] = (_Float16)EXP2(xb[idx] * L2E);
    }
    __syncthreads();

    // ---- phase B: DP ----
    float Ha[3][3], Hb[3][3];
    #pragma unroll
    for (int k = 0; k < 3; ++k)
        #pragma unroll
        for (int c = 0; c < 3; ++c) { Ha[k][c] = 0.0f; Hb[k][c] = 0.0f; }

    // prime FIFO: V[q] = exp diag q (f32), R[q] = raw f16 diag 4+q
    float V0[3], V1[3], V2[3], V3[3];
    _Float16 R0[3], R1[3], R2[3], R3[3];
    #pragma unroll
    for (int k = 0; k < 3; ++k) {
        const int jbk = jb0 + 150 * k;
        #pragma unroll
        for (int t = 0; t < 8; ++t) {
            int idx = 150 * ((149 + t) >> 1) + t - jbk;
            idx = idx < 0 ? 0 : idx;
            idx = idx > 22800 ? 22800 : idx;
            const _Float16 v = ldsH[idx];
            switch (t) {
                case 0: V0[k] = (float)v; break;
                case 1: V1[k] = (float)v; break;
                case 2: V2[k] = (float)v; break;
                case 3: V3[k] = (float)v; break;
                case 4: R0[k] = v; break;
                case 5: R1[k] = v; break;
                case 6: R2[k] = v; break;
                case 7: R3[k] = v; break;
            }
        }
    }

    float oneE = 1.0f;   // 2^-E
    float E = 0.0f;      // wave-uniform block-scale exponent
    float S = 0.0f;      // per-lane score sum, scaled by 2^-E

    for (int d = 0; d < 296; d += 4) {
        stepP<0>(d + 0, j3, jb0, ldsH, Hb, Ha, V0, V2, R0, oneE, S, isL50);
        stepP<1>(d + 1, j3, jb0, ldsH, Ha, Hb, V1, V3, R1, oneE, S, isL50);
        stepP<0>(d + 2, j3, jb0, ldsH, Hb, Ha, V2, V0, R2, oneE, S, isL50);
        stepP<1>(d + 3, j3, jb0, ldsH, Ha, Hb, V3, V1, R3, oneE, S, isL50);
        float m = Hb[0][0];
        m = fmaxf(m, Hb[0][1]); m = fmaxf(m, Hb[0][2]);
        m = fmaxf(m, Hb[1][0]); m = fmaxf(m, Hb[1][1]); m = fmaxf(m, Hb[1][2]);
        m = fmaxf(m, Hb[2][0]); m = fmaxf(m, Hb[2][1]); m = fmaxf(m, Hb[2][2]);
        const bool rn = __any(m > RTHR);
        const float sc = rn ? RSC : 1.0f;
        #pragma unroll
        for (int k = 0; k < 3; ++k)
            #pragma unroll
            for (int c = 0; c < 3; ++c) { Ha[k][c] *= sc; Hb[k][c] *= sc; }
        S *= sc; oneE *= sc; E += rn ? 64.0f : 0.0f;
    }
    // tail: diags 296..298
    stepP<0>(296, j3, jb0, ldsH, Hb, Ha, V0, V2, R0, oneE, S, isL50);
    stepP<1>(297, j3, jb0, ldsH, Ha, Hb, V1, V3, R1, oneE, S, isL50);
    stepP<0>(298, j3, jb0, ldsH, Hb, Ha, V2, V0, R2, oneE, S, isL50);

    // wave sum of S (E uniform across lanes)
    #pragma unroll
    for (int off = 32; off; off >>= 1) S += __shfl_xor(S, off, 64);
    if (lane == 0) {
        const float val = LN2 * (E + LOG2(S));
        if (use_atomic) atomicAdd(out_atomic, val);
        else            part[b] = val;
    }
}

__global__ __launch_bounds__(256)
void final_reduce(const float* __restrict__ part, float* __restrict__ out) {
    const int t = threadIdx.x;
    float v = part[t] + part[t + 256];
    #pragma unroll
    for (int off = 32; off; off >>= 1) v += __shfl_xor(v, off);
    __shared__ float ws[4];
    if ((t & 63) == 0) ws[t >> 6] = v;
    __syncthreads();
    if (t == 0) out[0] = ws[0] + ws[1] + ws[2] + ws[3];
}

extern "C" void kernel_launch(void* const* d_in, const int* in_sizes, int n_in,
                              void* d_out, int out_size, void* d_ws, size_t ws_size,
                              hipStream_t stream) {
    const float* x = (const float*)d_in[0];
    float* out = (float*)d_out;

    if (ws_size >= 512 * sizeof(float)) {
        float* part = (float*)d_ws;
        sw_pack<<<512, 64, 0, stream>>>(x, part, nullptr, 0);
        final_reduce<<<1, 256, 0, stream>>>(part, out);
    } else {
        hipMemsetAsync(out, 0, sizeof(float), stream);
        sw_pack<<<512, 64, 0, stream>>>(x, nullptr, out, 1);
    }
}

// Round 12
// 70.795 us; speedup vs baseline: 2.0013x; 1.2098x over previous
//
#include <hip/hip_runtime.h>

// Smith-Waterman soft-DP, B=512, x: (512,151,151) f32, scalar output.
// One wave per batch (512 blocks). Linear-domain DP (H = exp(h) * 2^-E).
// Phase A: coalesced read of x[b] (unroll x4), exp2 -> f16 row-major LDS.
// Phase B: slot packing j = 3*lane + k (2-3 bound-ctrl DPPs/step, no
// readlane); running scalar byte-base addressing (SALU) + v_sub + clamp;
// per-k S accumulators; renorm every 8 steps with early (step-6) decision
// applied after step 8; 8-step unrolled bodies; 4-step register FIFO.

#define CGO 6.737946999085467e-03f   // e^-5
#define CGE 3.678794411714423e-01f   // e^-1
#define L2E 1.4426950408889634f
#define LN2 0.6931471805599453f
#define RTHR 0x1p36f
#define RSC  0x1p-80f
#define EADD 80.0f

#if __has_builtin(__builtin_amdgcn_exp2f)
#define EXP2(x) __builtin_amdgcn_exp2f(x)
#else
static __device__ __forceinline__ float EXP2_(float x){float r;asm("v_exp_f32 %0, %1":"=v"(r):"v"(x));return r;}
#define EXP2(x) EXP2_(x)
#endif

#if __has_builtin(__builtin_amdgcn_logf)
#define LOG2(x) __builtin_amdgcn_logf(x)
#else
static __device__ __forceinline__ float LOG2_(float x){float r;asm("v_log_f32 %0, %1":"=v"(r):"v"(x));return r;}
#define LOG2(x) LOG2_(x)
#endif

#define DPP_UP 0x138   // wave_shr:1  (lane i <- i-1; lane 0 -> bound 0)
#define DPP_DN 0x130   // wave_shl:1  (lane i <- i+1; lane 63 -> bound 0)

template<int CTRL>
static __device__ __forceinline__ float dppz(float v){   // invalid lanes -> 0
    return __int_as_float(__builtin_amdgcn_update_dpp(
        0, __float_as_int(v), CTRL, 0xF, 0xF, true));
}

// ---- one anti-diagonal step (SO = d&1, compile-time) ----
// Slot j = 3*lane + k. Entry: Vs[k] = exp(cell) diag d, Vx[k] = diag d+2,
// Rc[k] = raw f16 diag d+4; sb = byte base of diag d+8's row-major address
// (wave-uniform; idx_byte = sb - 900*lane - 300*k). Issues LDS reads for
// diag d+8; commits Vs <- cvt(Rc), Rc <- new. H1 = h(d-1), H2 = h(d-2)
// (overwritten with h(d)).
template<int SO>
static __device__ __forceinline__
void stepP(const int d, const int j3, const int vjk0, int& sb,
           const _Float16* __restrict__ ldsH,
           float (&H1)[3][3], float (&H2)[3][3],
           float (&Vs)[3], float (&Vx)[3], _Float16 (&Rc)[3],
           const float oneE, float (&S)[3], const bool isL50)
{
    const int half = (149 + d) >> 1;
    const int cvlo = half - (d < 149 ? d : 149);
    const int cvhi = half - (d > 149 ? d - 149 : 0);

    // LDS reads for diag d+8 (consumed 4 steps later)
    _Float16 l[3];
    #pragma unroll
    for (int k = 0; k < 3; ++k) {
        int vb = sb - vjk0 - 300 * k;          // byte offset
        vb = vb < 0 ? 0 : vb;
        vb = vb > 45600 ? 45600 : vb;
        l[k] = *(const _Float16*)((const char*)ldsH + vb);
    }
    sb += SO ? 2 : 302;                        // advance to next diag's base

    // neighbor components under packed mapping (h1 = H1)
    float R0[3], R1[3], D0[3], D1[3], D2[3];
    if (SO) {   // odd: right <- h1[j-1]; down <- own h1
        R0[0] = dppz<DPP_UP>(H1[2][0]);     // j-1 = 3(lane-1)+2
        R1[0] = dppz<DPP_UP>(H1[2][1]);
        R0[1] = H1[0][0]; R1[1] = H1[0][1]; // j-1 = own k=0
        R0[2] = H1[1][0]; R1[2] = H1[1][1]; // j-1 = own k=1
        #pragma unroll
        for (int k = 0; k < 3; ++k) { D0[k]=H1[k][0]; D1[k]=H1[k][1]; D2[k]=H1[k][2]; }
    } else {    // even: right <- own h1; down <- h1[j+1]
        #pragma unroll
        for (int k = 0; k < 3; ++k) { R0[k]=H1[k][0]; R1[k]=H1[k][1]; }
        D0[0] = H1[1][0]; D1[0] = H1[1][1]; D2[0] = H1[1][2];  // j+1 = own k=1
        D0[1] = H1[2][0]; D1[1] = H1[2][1]; D2[1] = H1[2][2];  // j+1 = own k=2
        D0[2] = dppz<DPP_DN>(H1[0][0]);     // j+1 = 3(lane+1)+0
        D1[2] = dppz<DPP_DN>(H1[0][1]);
        D2[2] = dppz<DPP_DN>(H1[0][2]);
    }

    #pragma unroll
    for (int k = 0; k < 3; ++k) {
        const int j = j3 + k;
        const bool cv = (j >= cvlo) && (j <= cvhi);
        const float sxl = cv ? Vs[k] : 0.0f;
        const float x2l = cv ? Vx[k] : 0.0f;

        float h0 = sxl * ((H2[k][0] + H2[k][1]) + (H2[k][2] + oneE));
        float h1 = fmaf(CGO, R0[k], CGE * R1[k]);
        float h2 = fmaf(CGO, D0[k] + D1[k], CGE * D2[k]);
        if (k == 0) {   // slot 150 (lane 50, k=0) is the only pad slot a real
            h1 = isL50 ? 0.0f : h1;   // cell ever reads; force exact sentinel.
            h2 = isL50 ? 0.0f : h2;   // (h0 already 0 via cv.) Slots 151+ stay 0.
        }
        S[k] = fmaf(x2l, (h0 + h1) + h2, S[k]);
        H2[k][0] = h0; H2[k][1] = h1; H2[k][2] = h2;
    }

    // FIFO: commit (cvt) diag d+4, insert new raw diag d+8
    Vs[0] = (float)Rc[0]; Vs[1] = (float)Rc[1]; Vs[2] = (float)Rc[2];
    Rc[0] = l[0]; Rc[1] = l[1]; Rc[2] = l[2];
}

__global__ __launch_bounds__(64)
void sw_pack(const float* __restrict__ x, float* __restrict__ part,
             float* __restrict__ out_atomic, int use_atomic) {
    const int b = blockIdx.x;
    const float* xb = x + (size_t)b * 22801;
    const int lane = threadIdx.x;
    const int j3   = 3 * lane;      // slot of k=0
    const int vjk0 = 900 * lane;    // byte offset of k=0 slot (150*j*2B)
    const bool isL50 = (lane == 50);

    __shared__ _Float16 ldsH[22816];   // row-major exp2(x*log2e), f16

    // ---- phase A: coalesced load + exp into LDS (4 loads in flight) ----
    for (int ii = 0; ii < 89; ++ii) {
        const int base = ii * 256 + lane;
        const float a0 = xb[base];
        const float a1 = xb[base + 64];
        const float a2 = xb[base + 128];
        const float a3 = xb[base + 192];
        ldsH[base]       = (_Float16)EXP2(a0 * L2E);
        ldsH[base + 64]  = (_Float16)EXP2(a1 * L2E);
        ldsH[base + 128] = (_Float16)EXP2(a2 * L2E);
        ldsH[base + 192] = (_Float16)EXP2(a3 * L2E);
    }
    if (lane < 17) {
        const int idx = 22784 + lane;
        ldsH[idx] = (_Float16)EXP2(xb[idx] * L2E);
    }
    __syncthreads();

    // ---- phase B: DP ----
    float Ha[3][3], Hb[3][3];
    #pragma unroll
    for (int k = 0; k < 3; ++k)
        #pragma unroll
        for (int c = 0; c < 3; ++c) { Ha[k][c] = 0.0f; Hb[k][c] = 0.0f; }

    // prime FIFO: V[q] = exp diag q (f32), R[q] = raw f16 diag 4+q
    float V0[3], V1[3], V2[3], V3[3];
    _Float16 R0[3], R1[3], R2[3], R3[3];
    #pragma unroll
    for (int k = 0; k < 3; ++k) {
        const int jbk = 450 * lane + 150 * k;
        #pragma unroll
        for (int t = 0; t < 8; ++t) {
            int idx = 150 * ((149 + t) >> 1) + t - jbk;
            idx = idx < 0 ? 0 : idx;
            idx = idx > 22800 ? 22800 : idx;
            const _Float16 v = ldsH[idx];
            switch (t) {
                case 0: V0[k] = (float)v; break;
                case 1: V1[k] = (float)v; break;
                case 2: V2[k] = (float)v; break;
                case 3: V3[k] = (float)v; break;
                case 4: R0[k] = v; break;
                case 5: R1[k] = v; break;
                case 6: R2[k] = v; break;
                case 7: R3[k] = v; break;
            }
        }
    }

    int sb = 23416;      // byte base of diag 8's address at d=0 (2*11708)
    float oneE = 1.0f;   // 2^-E
    float E = 0.0f;      // wave-uniform block-scale exponent
    float S[3] = {0.0f, 0.0f, 0.0f};   // per-k score sums, scaled by 2^-E

    for (int d = 0; d < 296; d += 8) {
        stepP<0>(d + 0, j3, vjk0, sb, ldsH, Hb, Ha, V0, V2, R0, oneE, S, isL50);
        stepP<1>(d + 1, j3, vjk0, sb, ldsH, Ha, Hb, V1, V3, R1, oneE, S, isL50);
        stepP<0>(d + 2, j3, vjk0, sb, ldsH, Hb, Ha, V2, V0, R2, oneE, S, isL50);
        stepP<1>(d + 3, j3, vjk0, sb, ldsH, Ha, Hb, V3, V1, R3, oneE, S, isL50);
        stepP<0>(d + 4, j3, vjk0, sb, ldsH, Hb, Ha, V0, V2, R0, oneE, S, isL50);
        stepP<1>(d + 5, j3, vjk0, sb, ldsH, Ha, Hb, V1, V3, R1, oneE, S, isL50);
        stepP<0>(d + 6, j3, vjk0, sb, ldsH, Hb, Ha, V2, V0, R2, oneE, S, isL50);
        // renorm decision from h(d+6) (newest = Ha); applied after step d+7.
        // Safety: RTHR=2^36, worst 8-step growth 2^78.4, 1-step apply lag
        // 2^9.8 -> max at apply < 2^125 (finite); RSC=2^-80 keeps post-renorm
        // values >= 2^-44; E tracks scaling exactly.
        float m = Ha[0][0];
        m = fmaxf(m, Ha[0][1]); m = fmaxf(m, Ha[0][2]);
        m = fmaxf(m, Ha[1][0]); m = fmaxf(m, Ha[1][1]); m = fmaxf(m, Ha[1][2]);
        m = fmaxf(m, Ha[2][0]); m = fmaxf(m, Ha[2][1]); m = fmaxf(m, Ha[2][2]);
        const bool rn = __any(m > RTHR);
        const float sc = rn ? RSC : 1.0f;
        stepP<1>(d + 7, j3, vjk0, sb, ldsH, Ha, Hb, V3, V1, R3, oneE, S, isL50);
        #pragma unroll
        for (int k = 0; k < 3; ++k)
            #pragma unroll
            for (int c = 0; c < 3; ++c) { Ha[k][c] *= sc; Hb[k][c] *= sc; }
        S[0] *= sc; S[1] *= sc; S[2] *= sc;
        oneE *= sc; E += rn ? EADD : 0.0f;
    }
    // tail: diags 296..298 (FIFO phase: 296 % 4 == 0)
    stepP<0>(296, j3, vjk0, sb, ldsH, Hb, Ha, V0, V2, R0, oneE, S, isL50);
    stepP<1>(297, j3, vjk0, sb, ldsH, Ha, Hb, V1, V3, R1, oneE, S, isL50);
    stepP<0>(298, j3, vjk0, sb, ldsH, Hb, Ha, V2, V0, R2, oneE, S, isL50);

    // wave sum of S (E uniform across lanes)
    float St = (S[0] + S[1]) + S[2];
    #pragma unroll
    for (int off = 32; off; off >>= 1) St += __shfl_xor(St, off, 64);
    if (lane == 0) {
        const float val = LN2 * (E + LOG2(St));
        if (use_atomic) atomicAdd(out_atomic, val);
        else            part[b] = val;
    }
}

__global__ __launch_bounds__(256)
void final_reduce(const float* __restrict__ part, float* __restrict__ out) {
    const int t = threadIdx.x;
    float v = part[t] + part[t + 256];
    #pragma unroll
    for (int off = 32; off; off >>= 1) v += __shfl_xor(v, off);
    __shared__ float ws[4];
    if ((t & 63) == 0) ws[t >> 6] = v;
    __syncthreads();
    if (t == 0) out[0] = ws[0] + ws[1] + ws[2] + ws[3];
}

extern "C" void kernel_launch(void* const* d_in, const int* in_sizes, int n_in,
                              void* d_out, int out_size, void* d_ws, size_t ws_size,
                              hipStream_t stream) {
    const float* x = (const float*)d_in[0];
    float* out = (float*)d_out;

    if (ws_size >= 512 * sizeof(float)) {
        float* part = (float*)d_ws;
        sw_pack<<<512, 64, 0, stream>>>(x, part, nullptr, 0);
        final_reduce<<<1, 256, 0, stream>>>(part, out);
    } else {
        hipMemsetAsync(out, 0, sizeof(float), stream);
        sw_pack<<<512, 64, 0, stream>>>(x, nullptr, out, 1);
    }
}

// Round 13
// 61.082 us; speedup vs baseline: 2.3196x; 1.1590x over previous
//
#include <hip/hip_runtime.h>

// Smith-Waterman soft-DP, B=512, x: (512,151,151) f32, scalar output.
// One wave per batch (512 blocks). Linear-domain DP (H = exp(h) * 2^-E).
// Phase A: coalesced read of x[b], 16-deep ping-pong pipeline, exp2 -> f16
// row-major LDS (padded to 23104 halfs). Phase B: slot packing j=3*lane+k
// (2-3 bound-ctrl DPPs/step); commit-then-direct-load FIFO (loads go
// straight into the phase register consumed 4 steps later -> counted
// lgkmcnt, no per-step LDS wait); biased single-clamp addressing with
// ds-offset immediates; per-k S accumulators; renorm every 8 steps with
// early decision; 8-step unrolled bodies.

#define CGO 6.737946999085467e-03f   // e^-5
#define CGE 3.678794411714423e-01f   // e^-1
#define L2E 1.4426950408889634f
#define LN2 0.6931471805599453f
#define RTHR 0x1p36f
#define RSC  0x1p-80f
#define EADD 80.0f

#if __has_builtin(__builtin_amdgcn_exp2f)
#define EXP2(x) __builtin_amdgcn_exp2f(x)
#else
static __device__ __forceinline__ float EXP2_(float x){float r;asm("v_exp_f32 %0, %1":"=v"(r):"v"(x));return r;}
#define EXP2(x) EXP2_(x)
#endif

#if __has_builtin(__builtin_amdgcn_logf)
#define LOG2(x) __builtin_amdgcn_logf(x)
#else
static __device__ __forceinline__ float LOG2_(float x){float r;asm("v_log_f32 %0, %1":"=v"(r):"v"(x));return r;}
#define LOG2(x) LOG2_(x)
#endif

#define DPP_UP 0x138   // wave_shr:1  (lane i <- i-1; lane 0 -> bound 0)
#define DPP_DN 0x130   // wave_shl:1  (lane i <- i+1; lane 63 -> bound 0)

template<int CTRL>
static __device__ __forceinline__ float dppz(float v){   // invalid lanes -> 0
    return __int_as_float(__builtin_amdgcn_update_dpp(
        0, __float_as_int(v), CTRL, 0xF, 0xF, true));
}

// ---- one anti-diagonal step (SO = d&1, compile-time) ----
// Slot j = 3*lane + k. Entry: Vs[k] = exp(cell) diag d (f32), Vx[k] = diag
// d+2, Rc[k] = raw f16 diag d+4 (loaded at step d-4). sb = biased byte base
// for diag d+8 (wave-uniform; addr_k = clamp(sb - 900*lane) + 600-300k).
// Order: compute -> commit Vs<-cvt(Rc) -> load Rc<-lds(diag d+8).
template<int SO>
static __device__ __forceinline__
void stepP(const int d, const int j3, const int vjk0, int& sb,
           const _Float16* ldsH,
           float (&H1)[3][3], float (&H2)[3][3],
           float (&Vs)[3], float (&Vx)[3], _Float16 (&Rc)[3],
           const float oneE, float (&S)[3], const bool isL50)
{
    const int half = (149 + d) >> 1;
    const int cvlo = half - (d < 149 ? d : 149);
    const int cvhi = half - (d > 149 ? d - 149 : 0);

    // neighbor components under packed mapping (h1 = H1)
    float R0[3], R1[3], D0[3], D1[3], D2[3];
    if (SO) {   // odd: right <- h1[j-1]; down <- own h1
        R0[0] = dppz<DPP_UP>(H1[2][0]);     // j-1 = 3(lane-1)+2
        R1[0] = dppz<DPP_UP>(H1[2][1]);
        R0[1] = H1[0][0]; R1[1] = H1[0][1]; // j-1 = own k=0
        R0[2] = H1[1][0]; R1[2] = H1[1][1]; // j-1 = own k=1
        #pragma unroll
        for (int k = 0; k < 3; ++k) { D0[k]=H1[k][0]; D1[k]=H1[k][1]; D2[k]=H1[k][2]; }
    } else {    // even: right <- own h1; down <- h1[j+1]
        #pragma unroll
        for (int k = 0; k < 3; ++k) { R0[k]=H1[k][0]; R1[k]=H1[k][1]; }
        D0[0] = H1[1][0]; D1[0] = H1[1][1]; D2[0] = H1[1][2];  // j+1 = own k=1
        D0[1] = H1[2][0]; D1[1] = H1[2][1]; D2[1] = H1[2][2];  // j+1 = own k=2
        D0[2] = dppz<DPP_DN>(H1[0][0]);     // j+1 = 3(lane+1)+0
        D1[2] = dppz<DPP_DN>(H1[0][1]);
        D2[2] = dppz<DPP_DN>(H1[0][2]);
    }

    #pragma unroll
    for (int k = 0; k < 3; ++k) {
        const int j = j3 + k;
        const bool cv = (j >= cvlo) && (j <= cvhi);
        const float sxl = cv ? Vs[k] : 0.0f;
        const float x2l = cv ? Vx[k] : 0.0f;

        float h0 = sxl * ((H2[k][0] + H2[k][1]) + (H2[k][2] + oneE));
        float h1 = fmaf(CGO, R0[k], CGE * R1[k]);
        float h2 = fmaf(CGO, D0[k] + D1[k], CGE * D2[k]);
        if (k == 0) {   // slot 150 (lane 50, k=0) is the only pad slot a real
            h1 = isL50 ? 0.0f : h1;   // cell ever reads; force exact sentinel.
            h2 = isL50 ? 0.0f : h2;   // (h0 already 0 via cv.) Slots 151+ stay 0.
        }
        S[k] = fmaf(x2l, (h0 + h1) + h2, S[k]);
        H2[k][0] = h0; H2[k][1] = h1; H2[k][2] = h2;
    }

    // commit: Vs <- cvt(Rc)  [Rc holds x(d+4), loaded 4 steps ago -> counted
    // lgkmcnt wait covers only loads >= 4 steps old: no stall]
    Vs[0] = (float)Rc[0]; Vs[1] = (float)Rc[1]; Vs[2] = (float)Rc[2];

    // load diag d+8 DIRECTLY into Rc (consumed at step d+4; no reg move)
    int vb = sb - vjk0;
    vb = vb < 0 ? 0 : vb;
    vb = vb > 45600 ? 45600 : vb;
    const char* base = (const char*)ldsH + vb;
    Rc[0] = *(const _Float16*)(base + 600);
    Rc[1] = *(const _Float16*)(base + 300);
    Rc[2] = *(const _Float16*)(base + 0);
    sb += SO ? 2 : 302;
}

__global__ __launch_bounds__(64)
void sw_pack(const float* __restrict__ x, float* __restrict__ part,
             float* __restrict__ out_atomic, int use_atomic) {
    const int b = blockIdx.x;
    const float* xb = x + (size_t)b * 22801;
    const int lane = threadIdx.x;
    const int j3   = 3 * lane;      // slot of k=0
    const int vjk0 = 900 * lane;    // byte offset of k=0 slot (150*j*2B)
    const bool isL50 = (lane == 50);

    __shared__ _Float16 ldsH[23104];   // row-major exp2(x*log2e), f16 + pad

    // ---- zero the pad region [22816, 23104) ----
    for (int p = lane; p < 288; p += 64) ldsH[22816 + p] = (_Float16)0.0f;

    // ---- phase A: coalesced load + exp into LDS (16-deep ping-pong) ----
    {
        float va[16], vb_[16];
        #pragma unroll
        for (int u = 0; u < 16; ++u) va[u] = xb[u * 64 + lane];
        for (int g = 0; g < 22; g += 2) {
            #pragma unroll
            for (int u = 0; u < 16; ++u)
                vb_[u] = xb[((g + 1) * 16 + u) * 64 + lane];
            #pragma unroll
            for (int u = 0; u < 16; ++u)
                ldsH[(g * 16 + u) * 64 + lane] = (_Float16)EXP2(va[u] * L2E);
            if (g + 2 < 22) {
                #pragma unroll
                for (int u = 0; u < 16; ++u)
                    va[u] = xb[((g + 2) * 16 + u) * 64 + lane];
            }
            #pragma unroll
            for (int u = 0; u < 16; ++u)
                ldsH[((g + 1) * 16 + u) * 64 + lane] = (_Float16)EXP2(vb_[u] * L2E);
        }
        // iters 352..355 (floats 22528..22784)
        float vt[4];
        #pragma unroll
        for (int u = 0; u < 4; ++u) vt[u] = xb[(352 + u) * 64 + lane];
        #pragma unroll
        for (int u = 0; u < 4; ++u)
            ldsH[(352 + u) * 64 + lane] = (_Float16)EXP2(vt[u] * L2E);
        if (lane < 17) {
            const int idx = 22784 + lane;
            ldsH[idx] = (_Float16)EXP2(xb[idx] * L2E);
        }
    }
    __syncthreads();

    // ---- phase B: DP ----
    float Ha[3][3], Hb[3][3];
    #pragma unroll
    for (int k = 0; k < 3; ++k)
        #pragma unroll
        for (int c = 0; c < 3; ++c) { Ha[k][c] = 0.0f; Hb[k][c] = 0.0f; }

    // prime FIFO: V[q] = exp diag q (f32), R[q] = raw f16 diag 4+q
    float V0[3], V1[3], V2[3], V3[3];
    _Float16 R0[3], R1[3], R2[3], R3[3];
    #pragma unroll
    for (int k = 0; k < 3; ++k) {
        const int jbk = 450 * lane + 150 * k;
        #pragma unroll
        for (int t = 0; t < 8; ++t) {
            int idx = 150 * ((149 + t) >> 1) + t - jbk;
            idx = idx < 0 ? 0 : idx;
            idx = idx > 22800 ? 22800 : idx;
            const _Float16 v = ldsH[idx];
            switch (t) {
                case 0: V0[k] = (float)v; break;
                case 1: V1[k] = (float)v; break;
                case 2: V2[k] = (float)v; break;
                case 3: V3[k] = (float)v; break;
                case 4: R0[k] = v; break;
                case 5: R1[k] = v; break;
                case 6: R2[k] = v; break;
                case 7: R3[k] = v; break;
            }
        }
    }

    int sb = 22816;      // biased byte base for diag 8 at d=0 (23416 - 600)
    float oneE = 1.0f;   // 2^-E
    float E = 0.0f;      // wave-uniform block-scale exponent
    float S[3] = {0.0f, 0.0f, 0.0f};   // per-k score sums, scaled by 2^-E

    for (int d = 0; d < 296; d += 8) {
        stepP<0>(d + 0, j3, vjk0, sb, ldsH, Hb, Ha, V0, V2, R0, oneE, S, isL50);
        stepP<1>(d + 1, j3, vjk0, sb, ldsH, Ha, Hb, V1, V3, R1, oneE, S, isL50);
        stepP<0>(d + 2, j3, vjk0, sb, ldsH, Hb, Ha, V2, V0, R2, oneE, S, isL50);
        stepP<1>(d + 3, j3, vjk0, sb, ldsH, Ha, Hb, V3, V1, R3, oneE, S, isL50);
        stepP<0>(d + 4, j3, vjk0, sb, ldsH, Hb, Ha, V0, V2, R0, oneE, S, isL50);
        stepP<1>(d + 5, j3, vjk0, sb, ldsH, Ha, Hb, V1, V3, R1, oneE, S, isL50);
        stepP<0>(d + 6, j3, vjk0, sb, ldsH, Hb, Ha, V2, V0, R2, oneE, S, isL50);
        // renorm decision from h(d+6) (newest = Ha); applied after step d+7.
        // Safety: RTHR=2^36, worst 8-step growth 2^78.4, 1-step apply lag
        // 2^9.8 -> max at apply < 2^125 (finite); RSC=2^-80 keeps post-renorm
        // values >= 2^-44; E tracks scaling exactly.
        float m = Ha[0][0];
        m = fmaxf(m, Ha[0][1]); m = fmaxf(m, Ha[0][2]);
        m = fmaxf(m, Ha[1][0]); m = fmaxf(m, Ha[1][1]); m = fmaxf(m, Ha[1][2]);
        m = fmaxf(m, Ha[2][0]); m = fmaxf(m, Ha[2][1]); m = fmaxf(m, Ha[2][2]);
        const bool rn = __any(m > RTHR);
        const float sc = rn ? RSC : 1.0f;
        stepP<1>(d + 7, j3, vjk0, sb, ldsH, Ha, Hb, V3, V1, R3, oneE, S, isL50);
        #pragma unroll
        for (int k = 0; k < 3; ++k)
            #pragma unroll
            for (int c = 0; c < 3; ++c) { Ha[k][c] *= sc; Hb[k][c] *= sc; }
        S[0] *= sc; S[1] *= sc; S[2] *= sc;
        oneE *= sc; E += rn ? EADD : 0.0f;
    }
    // tail: diags 296..298 (FIFO phase: 296 % 4 == 0)
    stepP<0>(296, j3, vjk0, sb, ldsH, Hb, Ha, V0, V2, R0, oneE, S, isL50);
    stepP<1>(297, j3, vjk0, sb, ldsH, Ha, Hb, V1, V3, R1, oneE, S, isL50);
    stepP<0>(298, j3, vjk0, sb, ldsH, Hb, Ha, V2, V0, R2, oneE, S, isL50);

    // wave sum of S (E uniform across lanes)
    float St = (S[0] + S[1]) + S[2];
    #pragma unroll
    for (int off = 32; off; off >>= 1) St += __shfl_xor(St, off, 64);
    if (lane == 0) {
        const float val = LN2 * (E + LOG2(St));
        if (use_atomic) atomicAdd(out_atomic, val);
        else            part[b] = val;
    }
}

__global__ __launch_bounds__(256)
void final_reduce(const float* __restrict__ part, float* __restrict__ out) {
    const int t = threadIdx.x;
    float v = part[t] + part[t + 256];
    #pragma unroll
    for (int off = 32; off; off >>= 1) v += __shfl_xor(v, off);
    __shared__ float ws[4];
    if ((t & 63) == 0) ws[t >> 6] = v;
    __syncthreads();
    if (t == 0) out[0] = ws[0] + ws[1] + ws[2] + ws[3];
}

extern "C" void kernel_launch(void* const* d_in, const int* in_sizes, int n_in,
                              void* d_out, int out_size, void* d_ws, size_t ws_size,
                              hipStream_t stream) {
    const float* x = (const float*)d_in[0];
    float* out = (float*)d_out;

    if (ws_size >= 512 * sizeof(float)) {
        float* part = (float*)d_ws;
        sw_pack<<<512, 64, 0, stream>>>(x, part, nullptr, 0);
        final_reduce<<<1, 256, 0, stream>>>(part, out);
    } else {
        hipMemsetAsync(out, 0, sizeof(float), stream);
        sw_pack<<<512, 64, 0, stream>>>(x, nullptr, out, 1);
    }
}